// Round 2
// baseline (3496.912 us; speedup 1.0000x reference)
//
#include <hip/hip_runtime.h>
#include <hip/hip_bf16.h>
#include <stdint.h>

#define N_NODES 20000
#define DIM     768
#define NREL    8
#define NEDGE   320000
#define GK      6912   // NREL*DIM + DIM

typedef short short8 __attribute__((ext_vector_type(8)));
typedef float f32x4  __attribute__((ext_vector_type(4)));

__device__ __forceinline__ void async_load16(const void* g, void* l) {
  __builtin_amdgcn_global_load_lds((const __attribute__((address_space(1))) void*)g,
                                   (__attribute__((address_space(3))) void*)l,
                                   16, 0, 0);
}

__device__ __forceinline__ float bf16hi_to_f32(uint32_t hi16_in_low) {
  return __builtin_bit_cast(float, hi16_in_low << 16);
}

// ---------------------------------------------------------------- CSR build
__global__ void count_deg_kernel(const int* __restrict__ dst, int* __restrict__ deg, int e_cnt) {
  int e = blockIdx.x * 256 + threadIdx.x;
  if (e < e_cnt) atomicAdd(&deg[dst[e]], 1);
}

// single block, 1024 threads, wave-shuffle scan (3 barriers per 1024-chunk)
__global__ void scan_kernel(const int* __restrict__ deg, int* __restrict__ offs,
                            int* __restrict__ cursor, int n) {
  __shared__ int wsum[16];
  __shared__ int carry_s;
  const int t = threadIdx.x, lane = t & 63, wave = t >> 6;
  if (t == 0) carry_s = 0;
  __syncthreads();
  for (int base = 0; base < n; base += 1024) {
    int i = base + t;
    int v = (i < n) ? deg[i] : 0;
    int s = v;
#pragma unroll
    for (int off = 1; off < 64; off <<= 1) {
      int u = __shfl_up(s, off, 64);
      if (lane >= off) s += u;
    }
    if (lane == 63) wsum[wave] = s;
    __syncthreads();
    if (t < 16) {
      int w = wsum[t];
#pragma unroll
      for (int off = 1; off < 16; off <<= 1) {
        int u = __shfl_up(w, off, 64);
        if (t >= off) w += u;
      }
      wsum[t] = w;
    }
    __syncthreads();
    int c = carry_s;
    int basew = (wave > 0) ? wsum[wave - 1] : 0;
    int excl = c + basew + s - v;
    if (i < n) { offs[i] = excl; cursor[i] = excl; }
    __syncthreads();                 // everyone has read carry_s & wsum
    if (t == 0) carry_s = c + wsum[15];
    __syncthreads();
  }
  if (t == 0) offs[n] = carry_s;
}

__global__ void scatter_kernel(const int* __restrict__ src, const int* __restrict__ dst,
                               const int* __restrict__ et, int* __restrict__ cursor,
                               int* __restrict__ es, int* __restrict__ er, int e_cnt) {
  int e = blockIdx.x * 256 + threadIdx.x;
  if (e < e_cnt) {
    int d = dst[e];
    int p = atomicAdd(&cursor[d], 1);
    es[p] = src[e];
    er[p] = et[e];
  }
}

// ---------------------------------------------------------------- fp32 -> bf16
__global__ void cvt_bf16_kernel(const float4* __restrict__ in, ushort4* __restrict__ out, int n4) {
  int i = blockIdx.x * 256 + threadIdx.x;
  if (i < n4) {
    float4 f = in[i];
    ushort4 r;
    r.x = __builtin_bit_cast(unsigned short, __float2bfloat16(f.x));
    r.y = __builtin_bit_cast(unsigned short, __float2bfloat16(f.y));
    r.z = __builtin_bit_cast(unsigned short, __float2bfloat16(f.z));
    r.w = __builtin_bit_cast(unsigned short, __float2bfloat16(f.w));
    out[i] = r;
  }
}

// ------------------------------------------------- weight transpose (f32 src [rows][DIM] -> bf16 dst [DIM][GK])
__global__ void transpose_w_kernel(const float* __restrict__ src, __hip_bfloat16* __restrict__ dst,
                                   int rows, int col_off) {
  __shared__ float tile[32][33];
  const int c0 = blockIdx.x * 32;   // source col (= dst row)
  const int r0 = blockIdx.y * 32;   // source row (= dst col)
  const int tx = threadIdx.x, ty = threadIdx.y;  // 32x8
  for (int i = ty; i < 32; i += 8) {
    int r = r0 + i, c = c0 + tx;
    tile[i][tx] = (r < rows) ? src[(size_t)r * DIM + c] : 0.f;
  }
  __syncthreads();
  for (int i = ty; i < 32; i += 8) {
    int c = c0 + i, r = r0 + tx;     // c = dst row (output feature o), r = dst col (k)
    if (r < rows)
      dst[(size_t)c * GK + col_off + r] = __float2bfloat16(tile[tx][i]);
  }
}

// ---------------------------------------------------------------- aggregation
// one block per dst node, 4 waves process edges in parallel (every 4th edge),
// accumulating into LDS [8][768] fp32 via ds_add_f32 (fire-and-forget atomics;
// lane address stride = 2 floats -> 2-way bank aliasing = free).
__global__ __launch_bounds__(256) void aggregate_kernel(
    const __hip_bfloat16* __restrict__ feat,  // [N_NODES][DIM] bf16
    const int* __restrict__ offs, const int* __restrict__ es, const int* __restrict__ er,
    __hip_bfloat16* __restrict__ Abuf,        // [caprows][GK], chunk-local rows
    int node_base) {
  __shared__ float sums[NREL][DIM];
  __shared__ int cnt[NREL];
  const int t = threadIdx.x;
  const int lane = t & 63;
  const int wave = t >> 6;
  const int n = node_base + blockIdx.x;
  for (int i = t; i < NREL * DIM; i += 256) (&sums[0][0])[i] = 0.f;
  if (t < NREL) cnt[t] = 0;
  __syncthreads();
  const int beg = offs[n], end = offs[n + 1];
  for (int e = beg + wave; e < end; e += 4) {
    const int s = es[e];
    const int r = er[e];
    if (lane == 0) atomicAdd(&cnt[r], 1);
    const uint32_t* row = (const uint32_t*)(feat + (size_t)s * DIM); // 384 u32 (bf16x2)
    float* srow = &sums[r][0];
#pragma unroll
    for (int j = 0; j < 6; ++j) {
      uint32_t v = row[lane + 64 * j];
      atomicAdd(&srow[2 * (lane + 64 * j)],     bf16hi_to_f32(v));            // low bf16
      atomicAdd(&srow[2 * (lane + 64 * j) + 1], __builtin_bit_cast(float, v & 0xffff0000u)); // high bf16
    }
  }
  __syncthreads();
  __hip_bfloat16* arow = Abuf + (size_t)blockIdx.x * GK;
  const float* s0 = &sums[0][0];
  uint32_t* arow32 = (uint32_t*)arow;
  for (int i = t; i < NREL * DIM / 2; i += 256) {
    const int r = i / (DIM / 2);
    const float inv = 1.f / fmaxf((float)cnt[r], 1.f);
    const uint32_t lo = __builtin_bit_cast(unsigned short, __float2bfloat16(s0[2 * i] * inv));
    const uint32_t hi = __builtin_bit_cast(unsigned short, __float2bfloat16(s0[2 * i + 1] * inv));
    arow32[i] = lo | (hi << 16);
  }
  const uint32_t* xr = (const uint32_t*)(feat + (size_t)n * DIM);
  uint32_t* rootdst = (uint32_t*)(arow + NREL * DIM);
  for (int p = t; p < DIM / 2; p += 256) rootdst[p] = xr[p];
}

// ---------------------------------------------------------------- GEMM
// C[m,o] = sum_k A[m,k] * WT[o,k] (+bias), m97 structure: 128x128 tile, BK=64,
// global_load_lds width 16, XOR-swizzled [128][64] LDS tiles, 16x16x32 bf16 MFMA.
// grid.x = ntile (fast) so the 6 column-blocks of one m-panel co-run and share
// the A panel in L2 -> A fetched ~once from HBM.
__global__ __launch_bounds__(256, 3) void gemm_kernel(
    const __hip_bfloat16* __restrict__ A,   // [>=mtiles*128][GK] chunk-local
    const __hip_bfloat16* __restrict__ BT,  // [DIM][GK]
    const float* __restrict__ bias,         // [DIM]
    __hip_bfloat16* __restrict__ outb,      // mode 0: relu -> bf16 (global rows)
    float* __restrict__ outf,               // mode 1: plain -> f32 (global rows)
    int mvalid, int node_base, int mode) {
  __shared__ __hip_bfloat16 Asm[128][64];
  __shared__ __hip_bfloat16 Bsm[128][64];
  const int t = threadIdx.x;
  const int lane = t & 63;
  const int wave = t >> 6;
  const int m0 = blockIdx.y * 128;
  const int n0 = blockIdx.x * 128;

  const int srow = lane >> 3;
  const int sg = (lane & 7) ^ srow;
  const __hip_bfloat16* ag = A  + (size_t)(m0 + wave * 32 + srow) * GK + sg * 8;
  const __hip_bfloat16* bg = BT + (size_t)(n0 + wave * 32 + srow) * GK + sg * 8;

  f32x4 acc[4][4] = {};
  const int wm = (wave >> 1) * 64;
  const int wn = (wave & 1) * 64;
  const int ml = lane & 15;
  const int quad = lane >> 4;
  const int sw = ml & 7;

  for (int kt = 0; kt < GK / 64; ++kt) {
    __syncthreads();
#pragma unroll
    for (int ib = 0; ib < 4; ++ib)
      async_load16(ag + (size_t)ib * 8 * GK, &Asm[wave * 32 + ib * 8][0]);
#pragma unroll
    for (int ib = 0; ib < 4; ++ib)
      async_load16(bg + (size_t)ib * 8 * GK, &Bsm[wave * 32 + ib * 8][0]);
    ag += 64; bg += 64;
    __syncthreads();
#pragma unroll
    for (int ks = 0; ks < 2; ++ks) {
      const int go = (((ks * 4 + quad) ^ sw) * 8);
      short8 a[4], b[4];
#pragma unroll
      for (int i = 0; i < 4; ++i)
        a[i] = *(const short8*)&Asm[wm + i * 16 + ml][go];
#pragma unroll
      for (int i = 0; i < 4; ++i)
        b[i] = *(const short8*)&Bsm[wn + i * 16 + ml][go];
#pragma unroll
      for (int i = 0; i < 4; ++i)
#pragma unroll
        for (int j = 0; j < 4; ++j)
          acc[i][j] = __builtin_amdgcn_mfma_f32_16x16x32_bf16(a[i], b[j], acc[i][j], 0, 0, 0);
    }
  }

  float bcol[4];
#pragma unroll
  for (int nt = 0; nt < 4; ++nt) bcol[nt] = bias[n0 + wn + nt * 16 + ml];
#pragma unroll
  for (int mt = 0; mt < 4; ++mt) {
#pragma unroll
    for (int rr = 0; rr < 4; ++rr) {
      int row = m0 + wm + mt * 16 + quad * 4 + rr;
      if (row < mvalid) {
        size_t orow = (size_t)(node_base + row) * DIM;
#pragma unroll
        for (int nt = 0; nt < 4; ++nt) {
          int col = n0 + wn + nt * 16 + ml;
          float v = acc[mt][nt][rr] + bcol[nt];
          if (mode == 0) outb[orow + col] = __float2bfloat16(fmaxf(v, 0.f));
          else           outf[orow + col] = v;
        }
      }
    }
  }
}

// ---------------------------------------------------------------- launch
extern "C" void kernel_launch(void* const* d_in, const int* in_sizes, int n_in,
                              void* d_out, int out_size, void* d_ws, size_t ws_size,
                              hipStream_t stream) {
  const float* x     = (const float*)d_in[0];
  const int*   eidx  = (const int*)d_in[1];     // [2][E]
  const int*   etype = (const int*)d_in[2];
  const float* W1    = (const float*)d_in[3];
  const float* root1 = (const float*)d_in[4];
  const float* b1    = (const float*)d_in[5];
  const float* W2    = (const float*)d_in[6];
  const float* root2 = (const float*)d_in[7];
  const float* b2    = (const float*)d_in[8];
  float* out = (float*)d_out;
  const int* esrc_in = eidx;
  const int* edst_in = eidx + NEDGE;

  char* p = (char*)d_ws;
  auto alloc = [&](size_t bytes) -> char* {
    char* r = p;
    p += (bytes + 255) & ~(size_t)255;
    return r;
  };
  __hip_bfloat16* xb  = (__hip_bfloat16*)alloc((size_t)N_NODES * DIM * 2);
  __hip_bfloat16* hb  = (__hip_bfloat16*)alloc((size_t)N_NODES * DIM * 2);
  __hip_bfloat16* w1t = (__hip_bfloat16*)alloc((size_t)DIM * GK * 2);
  __hip_bfloat16* w2t = (__hip_bfloat16*)alloc((size_t)DIM * GK * 2);
  int* deg    = (int*)alloc((size_t)N_NODES * 4);
  int* offs   = (int*)alloc((size_t)(N_NODES + 1) * 4);
  int* cursor = (int*)alloc((size_t)N_NODES * 4);
  int* es     = (int*)alloc((size_t)NEDGE * 4);
  int* er     = (int*)alloc((size_t)NEDGE * 4);
  size_t used = (size_t)(p - (char*)d_ws);
  size_t remain = (ws_size > used) ? (ws_size - used) : 0;
  long long caprows_ll = (long long)(remain / ((size_t)GK * 2));
  int caprows = (int)((caprows_ll / 128) * 128);
  if (caprows > 20096) caprows = 20096;   // 157*128
  if (caprows < 128) caprows = 128;
  __hip_bfloat16* Abuf = (__hip_bfloat16*)p;

  // --- CSR build ---
  hipMemsetAsync(deg, 0, (size_t)N_NODES * 4, stream);
  count_deg_kernel<<<(NEDGE + 255) / 256, 256, 0, stream>>>(edst_in, deg, NEDGE);
  scan_kernel<<<1, 1024, 0, stream>>>(deg, offs, cursor, N_NODES);
  scatter_kernel<<<(NEDGE + 255) / 256, 256, 0, stream>>>(esrc_in, edst_in, etype, cursor, es, er, NEDGE);

  // --- convert x, build transposed bf16 weights ---
  cvt_bf16_kernel<<<((N_NODES * DIM / 4) + 255) / 256, 256, 0, stream>>>(
      (const float4*)x, (ushort4*)xb, N_NODES * DIM / 4);
  dim3 tb(32, 8);
  transpose_w_kernel<<<dim3(DIM / 32, (NREL * DIM) / 32), tb, 0, stream>>>(W1, w1t, NREL * DIM, 0);
  transpose_w_kernel<<<dim3(DIM / 32, DIM / 32), tb, 0, stream>>>(root1, w1t, DIM, NREL * DIM);
  transpose_w_kernel<<<dim3(DIM / 32, (NREL * DIM) / 32), tb, 0, stream>>>(W2, w2t, NREL * DIM, 0);
  transpose_w_kernel<<<dim3(DIM / 32, DIM / 32), tb, 0, stream>>>(root2, w2t, DIM, NREL * DIM);

  // --- layer 1: A = [mean_r(x) | x], h = relu(A @ W1cat + b1) -> bf16 ---
  for (int base = 0; base < N_NODES; base += caprows) {
    int rows = N_NODES - base; if (rows > caprows) rows = caprows;
    aggregate_kernel<<<rows, 256, 0, stream>>>(xb, offs, es, er, Abuf, base);
    dim3 grid(DIM / 128, (rows + 127) / 128);
    gemm_kernel<<<grid, 256, 0, stream>>>(Abuf, w1t, b1, hb, nullptr, rows, base, 0);
  }
  // --- layer 2: A = [mean_r(h) | h], out = A @ W2cat + b2 -> f32 ---
  for (int base = 0; base < N_NODES; base += caprows) {
    int rows = N_NODES - base; if (rows > caprows) rows = caprows;
    aggregate_kernel<<<rows, 256, 0, stream>>>(hb, offs, es, er, Abuf, base);
    dim3 grid(DIM / 128, (rows + 127) / 128);
    gemm_kernel<<<grid, 256, 0, stream>>>(Abuf, w2t, b2, nullptr, out, rows, base, 1);
  }
}

// Round 3
// 1612.144 us; speedup vs baseline: 2.1691x; 2.1691x over previous
//
#include <hip/hip_runtime.h>
#include <hip/hip_bf16.h>
#include <stdint.h>

#define N_NODES 20000
#define DIM     768
#define NREL    8
#define NEDGE   320000
#define GKA     6144   // NREL*DIM  (aggregated part of K)
#define GK      6912   // GKA + DIM (full K incl. root)
#define NPW     4      // nodes per wave in aggregate

typedef short short8 __attribute__((ext_vector_type(8)));
typedef float f32x4  __attribute__((ext_vector_type(4)));

__device__ __forceinline__ void async_load16(const void* g, void* l) {
  __builtin_amdgcn_global_load_lds((const __attribute__((address_space(1))) void*)g,
                                   (__attribute__((address_space(3))) void*)l,
                                   16, 0, 0);
}

__device__ __forceinline__ float bf_lo(uint32_t v) {
  return __builtin_bit_cast(float, v << 16);
}
__device__ __forceinline__ float bf_hi(uint32_t v) {
  return __builtin_bit_cast(float, v & 0xffff0000u);
}

// ---------------------------------------------------------------- CSR build
__global__ void count_deg_kernel(const int* __restrict__ dst, int* __restrict__ deg, int e_cnt) {
  int e = blockIdx.x * 256 + threadIdx.x;
  if (e < e_cnt) atomicAdd(&deg[dst[e]], 1);
}

// single block, 1024 threads, wave-shuffle scan
__global__ void scan_kernel(const int* __restrict__ deg, int* __restrict__ offs,
                            int* __restrict__ cursor, int n) {
  __shared__ int wsum[16];
  __shared__ int carry_s;
  const int t = threadIdx.x, lane = t & 63, wave = t >> 6;
  if (t == 0) carry_s = 0;
  __syncthreads();
  for (int base = 0; base < n; base += 1024) {
    int i = base + t;
    int v = (i < n) ? deg[i] : 0;
    int s = v;
#pragma unroll
    for (int off = 1; off < 64; off <<= 1) {
      int u = __shfl_up(s, off, 64);
      if (lane >= off) s += u;
    }
    if (lane == 63) wsum[wave] = s;
    __syncthreads();
    if (t < 16) {
      int w = wsum[t];
#pragma unroll
      for (int off = 1; off < 16; off <<= 1) {
        int u = __shfl_up(w, off, 64);
        if (t >= off) w += u;
      }
      wsum[t] = w;
    }
    __syncthreads();
    int c = carry_s;
    int basew = (wave > 0) ? wsum[wave - 1] : 0;
    int excl = c + basew + s - v;
    if (i < n) { offs[i] = excl; cursor[i] = excl; }
    __syncthreads();
    if (t == 0) carry_s = c + wsum[15];
    __syncthreads();
  }
  if (t == 0) offs[n] = carry_s;
}

__global__ void scatter_kernel(const int* __restrict__ src, const int* __restrict__ dst,
                               const int* __restrict__ et, int* __restrict__ cursor,
                               int* __restrict__ es, int* __restrict__ er, int e_cnt) {
  int e = blockIdx.x * 256 + threadIdx.x;
  if (e < e_cnt) {
    int d = dst[e];
    int p = atomicAdd(&cursor[d], 1);
    es[p] = src[e];
    er[p] = et[e];
  }
}

// ---------------------------------------------------------------- fp32 -> bf16
__global__ void cvt_bf16_kernel(const float4* __restrict__ in, ushort4* __restrict__ out, int n4) {
  int i = blockIdx.x * 256 + threadIdx.x;
  if (i < n4) {
    float4 f = in[i];
    ushort4 r;
    r.x = __builtin_bit_cast(unsigned short, __float2bfloat16(f.x));
    r.y = __builtin_bit_cast(unsigned short, __float2bfloat16(f.y));
    r.z = __builtin_bit_cast(unsigned short, __float2bfloat16(f.z));
    r.w = __builtin_bit_cast(unsigned short, __float2bfloat16(f.w));
    out[i] = r;
  }
}

// ------------------------------------------------- weight transpose (f32 src [rows][DIM] -> bf16 dst [DIM][GK])
__global__ void transpose_w_kernel(const float* __restrict__ src, __hip_bfloat16* __restrict__ dst,
                                   int rows, int col_off) {
  __shared__ float tile[32][33];
  const int c0 = blockIdx.x * 32;
  const int r0 = blockIdx.y * 32;
  const int tx = threadIdx.x, ty = threadIdx.y;  // 32x8
  for (int i = ty; i < 32; i += 8) {
    int r = r0 + i, c = c0 + tx;
    tile[i][tx] = (r < rows) ? src[(size_t)r * DIM + c] : 0.f;
  }
  __syncthreads();
  for (int i = ty; i < 32; i += 8) {
    int c = c0 + i, r = r0 + tx;
    if (r < rows)
      dst[(size_t)c * GK + col_off + r] = __float2bfloat16(tile[tx][i]);
  }
}

// ---------------------------------------------------------------- aggregation
// grid (node_groups, 6): each wave owns 128 features (lane = 1 u32 = 2 bf16)
// and NPW nodes. Per edge: one coalesced 256B gather, accumulate into 16 VGPRs
// via wave-uniform switch on relation; per-relation counts kept in registers.
// Gathers batched x4 for vmcnt pipelining. No LDS.
__global__ __launch_bounds__(256) void aggregate_kernel(
    const __hip_bfloat16* __restrict__ feat,  // [N_NODES][DIM] bf16
    const int* __restrict__ offs, const int* __restrict__ es, const int* __restrict__ er,
    __hip_bfloat16* __restrict__ Abuf,        // [caprows][GKA], chunk-local rows
    int node_base, int rows) {
  const int t = threadIdx.x;
  const int lane = t & 63;
  const int wave = t >> 6;
  const int colbase = blockIdx.y * 128 + lane * 2;

  int nloc = (blockIdx.x * 4 + wave) * NPW;
  for (int it = 0; it < NPW; ++it, ++nloc) {
    if (nloc >= rows) return;
    const int n = node_base + nloc;
    const int beg = offs[n], end = offs[n + 1];
    float acc[16];
    int cnt[8];
#pragma unroll
    for (int i = 0; i < 16; ++i) acc[i] = 0.f;
#pragma unroll
    for (int i = 0; i < 8; ++i) cnt[i] = 0;

    for (int eb = beg; eb < end; eb += 4) {
      int m = end - eb; if (m > 4) m = 4;
      uint32_t v[4]; int rr[4];
#pragma unroll
      for (int j = 0; j < 4; ++j) {
        if (j < m) {
          const int s = es[eb + j];
          rr[j] = er[eb + j];
          v[j] = *(const uint32_t*)(feat + (size_t)s * DIM + colbase);
        }
      }
#pragma unroll
      for (int j = 0; j < 4; ++j) {
        if (j < m) {
          const float lo = bf_lo(v[j]), hi = bf_hi(v[j]);
          switch (rr[j]) {   // wave-uniform branch
            case 0: acc[0]  += lo; acc[1]  += hi; cnt[0]++; break;
            case 1: acc[2]  += lo; acc[3]  += hi; cnt[1]++; break;
            case 2: acc[4]  += lo; acc[5]  += hi; cnt[2]++; break;
            case 3: acc[6]  += lo; acc[7]  += hi; cnt[3]++; break;
            case 4: acc[8]  += lo; acc[9]  += hi; cnt[4]++; break;
            case 5: acc[10] += lo; acc[11] += hi; cnt[5]++; break;
            case 6: acc[12] += lo; acc[13] += hi; cnt[6]++; break;
            default: acc[14] += lo; acc[15] += hi; cnt[7]++; break;
          }
        }
      }
    }
#pragma unroll
    for (int r = 0; r < 8; ++r) {
      const float inv = 1.f / fmaxf((float)cnt[r], 1.f);
      const uint32_t lo = __builtin_bit_cast(unsigned short, __float2bfloat16(acc[2 * r] * inv));
      const uint32_t hi = __builtin_bit_cast(unsigned short, __float2bfloat16(acc[2 * r + 1] * inv));
      *(uint32_t*)(Abuf + (size_t)nloc * GKA + r * DIM + colbase) = lo | (hi << 16);
    }
  }
}

// ---------------------------------------------------------------- GEMM
// C[m,o] = sum_k Acat[m,k] * WT[o,k] (+bias).  Acat = [Amean (6144) | feat (768)]
// read as two K-segments (no root copy materialized). m97 structure: 128x128
// tile, BK=64, global_load_lds width 16, XOR-swizzled LDS, 16x16x32 bf16 MFMA.
// grid.x = ntile (fast) so column-blocks of one m-panel co-run -> A ~once from HBM.
__global__ __launch_bounds__(256, 3) void gemm_kernel(
    const __hip_bfloat16* __restrict__ A,     // [rows][GKA] chunk-local
    const __hip_bfloat16* __restrict__ feat,  // [N_NODES][DIM] root operand
    const __hip_bfloat16* __restrict__ BT,    // [DIM][GK]
    const float* __restrict__ bias,           // [DIM]
    __hip_bfloat16* __restrict__ outb,        // mode 0: relu -> bf16 (global rows)
    float* __restrict__ outf,                 // mode 1: plain -> f32 (global rows)
    int mvalid, int node_base, int mode) {
  __shared__ __hip_bfloat16 Asm[128][64];
  __shared__ __hip_bfloat16 Bsm[128][64];
  const int t = threadIdx.x;
  const int lane = t & 63;
  const int wave = t >> 6;
  const int m0 = blockIdx.y * 128;
  const int n0 = blockIdx.x * 128;

  const int srow = lane >> 3;
  const int sg = (lane & 7) ^ srow;
  const int arow = m0 + wave * 32 + srow;
  const __hip_bfloat16* ag = A  + (size_t)arow * GKA + sg * 8;
  const __hip_bfloat16* fg = feat + (size_t)(node_base + arow) * DIM + sg * 8;
  const __hip_bfloat16* bg = BT + (size_t)(n0 + wave * 32 + srow) * GK + sg * 8;

  f32x4 acc[4][4] = {};
  const int wm = (wave >> 1) * 64;
  const int wn = (wave & 1) * 64;
  const int ml = lane & 15;
  const int quad = lane >> 4;
  const int sw = ml & 7;

#define KSTEP(APTR, ASTRIDE)                                                       \
  {                                                                                \
    __syncthreads();                                                               \
    _Pragma("unroll")                                                              \
    for (int ib = 0; ib < 4; ++ib)                                                 \
      async_load16(APTR + (size_t)ib * 8 * (ASTRIDE), &Asm[wave * 32 + ib * 8][0]);\
    _Pragma("unroll")                                                              \
    for (int ib = 0; ib < 4; ++ib)                                                 \
      async_load16(bg + (size_t)ib * 8 * GK, &Bsm[wave * 32 + ib * 8][0]);         \
    bg += 64;                                                                      \
    __syncthreads();                                                               \
    _Pragma("unroll")                                                              \
    for (int ks = 0; ks < 2; ++ks) {                                               \
      const int go = (((ks * 4 + quad) ^ sw) * 8);                                 \
      short8 a[4], b[4];                                                           \
      _Pragma("unroll")                                                            \
      for (int i = 0; i < 4; ++i) a[i] = *(const short8*)&Asm[wm + i * 16 + ml][go];\
      _Pragma("unroll")                                                            \
      for (int i = 0; i < 4; ++i) b[i] = *(const short8*)&Bsm[wn + i * 16 + ml][go];\
      _Pragma("unroll")                                                            \
      for (int i = 0; i < 4; ++i)                                                  \
        _Pragma("unroll")                                                          \
        for (int j = 0; j < 4; ++j)                                                \
          acc[i][j] = __builtin_amdgcn_mfma_f32_16x16x32_bf16(a[i], b[j], acc[i][j], 0, 0, 0); \
    }                                                                              \
  }

  for (int kt = 0; kt < GKA / 64; ++kt) {   // 96 k-tiles from mean buffer
    KSTEP(ag, GKA);
    ag += 64;
  }
  for (int kt = 0; kt < DIM / 64; ++kt) {   // 12 k-tiles from root operand
    KSTEP(fg, DIM);
    fg += 64;
  }
#undef KSTEP

  float bcol[4];
#pragma unroll
  for (int nt = 0; nt < 4; ++nt) bcol[nt] = bias[n0 + wn + nt * 16 + ml];
#pragma unroll
  for (int mt = 0; mt < 4; ++mt) {
#pragma unroll
    for (int rr = 0; rr < 4; ++rr) {
      int row = m0 + wm + mt * 16 + quad * 4 + rr;
      if (row < mvalid) {
        size_t orow = (size_t)(node_base + row) * DIM;
#pragma unroll
        for (int nt = 0; nt < 4; ++nt) {
          int col = n0 + wn + nt * 16 + ml;
          float v = acc[mt][nt][rr] + bcol[nt];
          if (mode == 0) outb[orow + col] = __float2bfloat16(fmaxf(v, 0.f));
          else           outf[orow + col] = v;
        }
      }
    }
  }
}

// ---------------------------------------------------------------- launch
extern "C" void kernel_launch(void* const* d_in, const int* in_sizes, int n_in,
                              void* d_out, int out_size, void* d_ws, size_t ws_size,
                              hipStream_t stream) {
  const float* x     = (const float*)d_in[0];
  const int*   eidx  = (const int*)d_in[1];     // [2][E]
  const int*   etype = (const int*)d_in[2];
  const float* W1    = (const float*)d_in[3];
  const float* root1 = (const float*)d_in[4];
  const float* b1    = (const float*)d_in[5];
  const float* W2    = (const float*)d_in[6];
  const float* root2 = (const float*)d_in[7];
  const float* b2    = (const float*)d_in[8];
  float* out = (float*)d_out;
  const int* esrc_in = eidx;
  const int* edst_in = eidx + NEDGE;

  char* p = (char*)d_ws;
  auto alloc = [&](size_t bytes) -> char* {
    char* r = p;
    p += (bytes + 255) & ~(size_t)255;
    return r;
  };
  __hip_bfloat16* xb  = (__hip_bfloat16*)alloc((size_t)N_NODES * DIM * 2);
  __hip_bfloat16* hb  = (__hip_bfloat16*)alloc((size_t)N_NODES * DIM * 2);
  __hip_bfloat16* w1t = (__hip_bfloat16*)alloc((size_t)DIM * GK * 2);
  __hip_bfloat16* w2t = (__hip_bfloat16*)alloc((size_t)DIM * GK * 2);
  int* deg    = (int*)alloc((size_t)N_NODES * 4);
  int* offs   = (int*)alloc((size_t)(N_NODES + 1) * 4);
  int* cursor = (int*)alloc((size_t)N_NODES * 4);
  int* es     = (int*)alloc((size_t)NEDGE * 4);
  int* er     = (int*)alloc((size_t)NEDGE * 4);
  size_t used = (size_t)(p - (char*)d_ws);
  size_t remain = (ws_size > used) ? (ws_size - used) : 0;
  long long caprows_ll = (long long)(remain / ((size_t)GKA * 2));
  int caprows = (int)((caprows_ll / 128) * 128);
  if (caprows > 20096) caprows = 20096;   // 157*128
  if (caprows < 128) caprows = 128;
  __hip_bfloat16* Abuf = (__hip_bfloat16*)p;

  // --- CSR build ---
  hipMemsetAsync(deg, 0, (size_t)N_NODES * 4, stream);
  count_deg_kernel<<<(NEDGE + 255) / 256, 256, 0, stream>>>(edst_in, deg, NEDGE);
  scan_kernel<<<1, 1024, 0, stream>>>(deg, offs, cursor, N_NODES);
  scatter_kernel<<<(NEDGE + 255) / 256, 256, 0, stream>>>(esrc_in, edst_in, etype, cursor, es, er, NEDGE);

  // --- convert x, build transposed bf16 weights ---
  cvt_bf16_kernel<<<((N_NODES * DIM / 4) + 255) / 256, 256, 0, stream>>>(
      (const float4*)x, (ushort4*)xb, N_NODES * DIM / 4);
  dim3 tb(32, 8);
  transpose_w_kernel<<<dim3(DIM / 32, (NREL * DIM) / 32), tb, 0, stream>>>(W1, w1t, NREL * DIM, 0);
  transpose_w_kernel<<<dim3(DIM / 32, DIM / 32), tb, 0, stream>>>(root1, w1t, DIM, NREL * DIM);
  transpose_w_kernel<<<dim3(DIM / 32, (NREL * DIM) / 32), tb, 0, stream>>>(W2, w2t, NREL * DIM, 0);
  transpose_w_kernel<<<dim3(DIM / 32, DIM / 32), tb, 0, stream>>>(root2, w2t, DIM, NREL * DIM);

  // --- layer 1: h = relu([mean_r(x) | x] @ W1cat + b1) -> bf16 ---
  for (int base = 0; base < N_NODES; base += caprows) {
    int rows = N_NODES - base; if (rows > caprows) rows = caprows;
    dim3 agrid((rows + 4 * NPW - 1) / (4 * NPW), 6);
    aggregate_kernel<<<agrid, 256, 0, stream>>>(xb, offs, es, er, Abuf, base, rows);
    dim3 grid(DIM / 128, (rows + 127) / 128);
    gemm_kernel<<<grid, 256, 0, stream>>>(Abuf, xb, w1t, b1, hb, nullptr, rows, base, 0);
  }
  // --- layer 2: out = [mean_r(h) | h] @ W2cat + b2 -> f32 ---
  for (int base = 0; base < N_NODES; base += caprows) {
    int rows = N_NODES - base; if (rows > caprows) rows = caprows;
    dim3 agrid((rows + 4 * NPW - 1) / (4 * NPW), 6);
    aggregate_kernel<<<agrid, 256, 0, stream>>>(hb, offs, es, er, Abuf, base, rows);
    dim3 grid(DIM / 128, (rows + 127) / 128);
    gemm_kernel<<<grid, 256, 0, stream>>>(Abuf, hb, w2t, b2, nullptr, out, rows, base, 1);
  }
}

// Round 4
// 1110.626 us; speedup vs baseline: 3.1486x; 1.4516x over previous
//
#include <hip/hip_runtime.h>
#include <hip/hip_bf16.h>
#include <stdint.h>

#define N_NODES 20000
#define DIM     768
#define NREL    8
#define NEDGE   320000
#define NSEG    (N_NODES * NREL)   // 160000
#define GKA     6144   // NREL*DIM  (aggregated part of K)
#define GK      6912   // GKA + DIM (full K incl. root)
#define NPW     2      // nodes per wave in aggregate

typedef short short8 __attribute__((ext_vector_type(8)));
typedef float f32x4  __attribute__((ext_vector_type(4)));

__device__ __forceinline__ void async_load16(const void* g, void* l) {
  __builtin_amdgcn_global_load_lds((const __attribute__((address_space(1))) void*)g,
                                   (__attribute__((address_space(3))) void*)l,
                                   16, 0, 0);
}

__device__ __forceinline__ float bf_lo(uint32_t v) {
  return __builtin_bit_cast(float, v << 16);
}
__device__ __forceinline__ float bf_hi(uint32_t v) {
  return __builtin_bit_cast(float, v & 0xffff0000u);
}
__device__ __forceinline__ uint32_t pack_bf16x2(float a, float b) {
  uint32_t lo = __builtin_bit_cast(unsigned short, __float2bfloat16(a));
  uint32_t hi = __builtin_bit_cast(unsigned short, __float2bfloat16(b));
  return lo | (hi << 16);
}

// ---------------------------------------------------------------- segment CSR build
__global__ void seg_count_kernel(const int* __restrict__ dst, const int* __restrict__ et,
                                 int* __restrict__ segcnt, int e_cnt) {
  int e = blockIdx.x * 256 + threadIdx.x;
  if (e < e_cnt) atomicAdd(&segcnt[dst[e] * NREL + et[e]], 1);
}

// hierarchical scan over NSEG bins: per-block exclusive scan + partials
__global__ void block_scan_kernel(const int* __restrict__ in, int* __restrict__ out,
                                  int* __restrict__ partials, int n) {
  __shared__ int wsum[16];
  const int t = threadIdx.x, lane = t & 63, wave = t >> 6;
  const int i = blockIdx.x * 1024 + t;
  int v = (i < n) ? in[i] : 0;
  int s = v;
#pragma unroll
  for (int off = 1; off < 64; off <<= 1) {
    int u = __shfl_up(s, off, 64);
    if (lane >= off) s += u;
  }
  if (lane == 63) wsum[wave] = s;
  __syncthreads();
  if (t < 16) {
    int w = wsum[t];
#pragma unroll
    for (int off = 1; off < 16; off <<= 1) {
      int u = __shfl_up(w, off, 64);
      if (t >= off) w += u;
    }
    wsum[t] = w;
  }
  __syncthreads();
  const int basew = (wave > 0) ? wsum[wave - 1] : 0;
  if (i < n) out[i] = basew + s - v;        // block-local exclusive
  if (t == 1023) partials[blockIdx.x] = wsum[15];
}

// single-wave scan of block partials (in place, exclusive)
__global__ void partial_scan_kernel(int* __restrict__ partials, int nb) {
  const int lane = threadIdx.x & 63;
  int carry = 0;
  for (int base = 0; base < nb; base += 64) {
    const int i = base + lane;
    int v = (i < nb) ? partials[i] : 0;
    int s = v;
#pragma unroll
    for (int off = 1; off < 64; off <<= 1) {
      int u = __shfl_up(s, off, 64);
      if (lane >= off) s += u;
    }
    if (i < nb) partials[i] = carry + s - v;
    carry += __shfl(s, 63, 64);
  }
}

__global__ void add_offsets_kernel(int* __restrict__ soffs, const int* __restrict__ partials,
                                   int* __restrict__ cursor, int n) {
  const int i = blockIdx.x * 1024 + threadIdx.x;   // blockDim must be 1024
  if (i < n) {
    const int v = soffs[i] + partials[blockIdx.x];
    soffs[i] = v;
    cursor[i] = v;
  }
  if (i == 0) soffs[n] = NEDGE;
}

__global__ void seg_scatter_kernel(const int* __restrict__ src, const int* __restrict__ dst,
                                   const int* __restrict__ et, int* __restrict__ cursor,
                                   int* __restrict__ es, int e_cnt) {
  int e = blockIdx.x * 256 + threadIdx.x;
  if (e < e_cnt) {
    const int seg = dst[e] * NREL + et[e];
    const int p = atomicAdd(&cursor[seg], 1);
    es[p] = src[e];
  }
}

// ---------------------------------------------------------------- fp32 -> bf16
__global__ void cvt_bf16_kernel(const float4* __restrict__ in, ushort4* __restrict__ out, int n4) {
  int i = blockIdx.x * 256 + threadIdx.x;
  if (i < n4) {
    float4 f = in[i];
    ushort4 r;
    r.x = __builtin_bit_cast(unsigned short, __float2bfloat16(f.x));
    r.y = __builtin_bit_cast(unsigned short, __float2bfloat16(f.y));
    r.z = __builtin_bit_cast(unsigned short, __float2bfloat16(f.z));
    r.w = __builtin_bit_cast(unsigned short, __float2bfloat16(f.w));
    out[i] = r;
  }
}

// ------------------------------------------------- weight transpose (f32 src [rows][DIM] -> bf16 dst [DIM][GK])
__global__ void transpose_w_kernel(const float* __restrict__ src, __hip_bfloat16* __restrict__ dst,
                                   int rows, int col_off) {
  __shared__ float tile[32][33];
  const int c0 = blockIdx.x * 32;
  const int r0 = blockIdx.y * 32;
  const int tx = threadIdx.x, ty = threadIdx.y;  // 32x8
  for (int i = ty; i < 32; i += 8) {
    int r = r0 + i, c = c0 + tx;
    tile[i][tx] = (r < rows) ? src[(size_t)r * DIM + c] : 0.f;
  }
  __syncthreads();
  for (int i = ty; i < 32; i += 8) {
    int c = c0 + i, r = r0 + tx;
    if (r < rows)
      dst[(size_t)c * GK + col_off + r] = __float2bfloat16(tile[tx][i]);
  }
}

// ---------------------------------------------------------------- aggregation
// Edges pre-sorted by (dst, rel): soffs[n*8+r] gives each (node,rel) segment.
// One wave owns a full 768-feature row: lane holds 12 bf16 (3x dwordx2 at
// byte offsets lane*8 + {0,512,1024}). Only 12 live accumulators (current
// segment). No relation switch, no er loads; cnt = segment length. Empty
// segments naturally write zeros. Edge loop 2-way unrolled (6 gathers in flight).
__global__ __launch_bounds__(256) void aggregate_kernel(
    const __hip_bfloat16* __restrict__ feat,  // [N_NODES][DIM] bf16
    const int* __restrict__ soffs, const int* __restrict__ es,
    __hip_bfloat16* __restrict__ Abuf,        // [caprows][GKA], chunk-local rows
    int node_base, int rows) {
  const int t = threadIdx.x;
  const int lane = t & 63;
  const int wave = t >> 6;
  const int boff = lane * 8;                  // byte offset within 512B third

  int nloc = (blockIdx.x * 4 + wave) * NPW;
  for (int it = 0; it < NPW; ++it, ++nloc) {
    if (nloc >= rows) return;
    const int n = node_base + nloc;
    char* Ab = (char*)(Abuf + (size_t)nloc * GKA);
#pragma unroll
    for (int r = 0; r < NREL; ++r) {
      const int beg = soffs[n * NREL + r], end = soffs[n * NREL + r + 1];
      float acc[12];
#pragma unroll
      for (int i = 0; i < 12; ++i) acc[i] = 0.f;
      int e = beg;
      for (; e + 2 <= end; e += 2) {
        const int s0 = es[e], s1 = es[e + 1];
        const char* p0 = (const char*)(feat + (size_t)s0 * DIM) + boff;
        const char* p1 = (const char*)(feat + (size_t)s1 * DIM) + boff;
        const uint2 a0 = *(const uint2*)(p0);
        const uint2 a1 = *(const uint2*)(p0 + 512);
        const uint2 a2 = *(const uint2*)(p0 + 1024);
        const uint2 b0 = *(const uint2*)(p1);
        const uint2 b1 = *(const uint2*)(p1 + 512);
        const uint2 b2 = *(const uint2*)(p1 + 1024);
        acc[0]  += bf_lo(a0.x); acc[1]  += bf_hi(a0.x);
        acc[2]  += bf_lo(a0.y); acc[3]  += bf_hi(a0.y);
        acc[4]  += bf_lo(a1.x); acc[5]  += bf_hi(a1.x);
        acc[6]  += bf_lo(a1.y); acc[7]  += bf_hi(a1.y);
        acc[8]  += bf_lo(a2.x); acc[9]  += bf_hi(a2.x);
        acc[10] += bf_lo(a2.y); acc[11] += bf_hi(a2.y);
        acc[0]  += bf_lo(b0.x); acc[1]  += bf_hi(b0.x);
        acc[2]  += bf_lo(b0.y); acc[3]  += bf_hi(b0.y);
        acc[4]  += bf_lo(b1.x); acc[5]  += bf_hi(b1.x);
        acc[6]  += bf_lo(b1.y); acc[7]  += bf_hi(b1.y);
        acc[8]  += bf_lo(b2.x); acc[9]  += bf_hi(b2.x);
        acc[10] += bf_lo(b2.y); acc[11] += bf_hi(b2.y);
      }
      if (e < end) {
        const int s0 = es[e];
        const char* p0 = (const char*)(feat + (size_t)s0 * DIM) + boff;
        const uint2 a0 = *(const uint2*)(p0);
        const uint2 a1 = *(const uint2*)(p0 + 512);
        const uint2 a2 = *(const uint2*)(p0 + 1024);
        acc[0]  += bf_lo(a0.x); acc[1]  += bf_hi(a0.x);
        acc[2]  += bf_lo(a0.y); acc[3]  += bf_hi(a0.y);
        acc[4]  += bf_lo(a1.x); acc[5]  += bf_hi(a1.x);
        acc[6]  += bf_lo(a1.y); acc[7]  += bf_hi(a1.y);
        acc[8]  += bf_lo(a2.x); acc[9]  += bf_hi(a2.x);
        acc[10] += bf_lo(a2.y); acc[11] += bf_hi(a2.y);
      }
      const float inv = 1.f / fmaxf((float)(end - beg), 1.f);
      uint2 o0, o1, o2;
      o0.x = pack_bf16x2(acc[0] * inv, acc[1] * inv);
      o0.y = pack_bf16x2(acc[2] * inv, acc[3] * inv);
      o1.x = pack_bf16x2(acc[4] * inv, acc[5] * inv);
      o1.y = pack_bf16x2(acc[6] * inv, acc[7] * inv);
      o2.x = pack_bf16x2(acc[8] * inv, acc[9] * inv);
      o2.y = pack_bf16x2(acc[10] * inv, acc[11] * inv);
      char* dst = Ab + r * (DIM * 2);
      *(uint2*)(dst + boff) = o0;
      *(uint2*)(dst + boff + 512) = o1;
      *(uint2*)(dst + boff + 1024) = o2;
    }
  }
}

// ---------------------------------------------------------------- GEMM
// C[m,o] = sum_k Acat[m,k] * WT[o,k] (+bias).  Acat = [Amean (6144) | feat (768)]
// read as two K-segments (no root copy materialized). m97 structure: 128x128
// tile, BK=64, global_load_lds width 16, XOR-swizzled LDS, 16x16x32 bf16 MFMA.
// grid.x = ntile (fast) so column-blocks of one m-panel co-run -> A ~once from HBM.
__global__ __launch_bounds__(256, 3) void gemm_kernel(
    const __hip_bfloat16* __restrict__ A,     // [rows][GKA] chunk-local
    const __hip_bfloat16* __restrict__ feat,  // [N_NODES][DIM] root operand
    const __hip_bfloat16* __restrict__ BT,    // [DIM][GK]
    const float* __restrict__ bias,           // [DIM]
    __hip_bfloat16* __restrict__ outb,        // mode 0: relu -> bf16 (global rows)
    float* __restrict__ outf,                 // mode 1: plain -> f32 (global rows)
    int mvalid, int node_base, int mode) {
  __shared__ __hip_bfloat16 Asm[128][64];
  __shared__ __hip_bfloat16 Bsm[128][64];
  const int t = threadIdx.x;
  const int lane = t & 63;
  const int wave = t >> 6;
  const int m0 = blockIdx.y * 128;
  const int n0 = blockIdx.x * 128;

  const int srow = lane >> 3;
  const int sg = (lane & 7) ^ srow;
  const int arow = m0 + wave * 32 + srow;
  const __hip_bfloat16* ag = A  + (size_t)arow * GKA + sg * 8;
  const __hip_bfloat16* fg = feat + (size_t)(node_base + arow) * DIM + sg * 8;
  const __hip_bfloat16* bg = BT + (size_t)(n0 + wave * 32 + srow) * GK + sg * 8;

  f32x4 acc[4][4] = {};
  const int wm = (wave >> 1) * 64;
  const int wn = (wave & 1) * 64;
  const int ml = lane & 15;
  const int quad = lane >> 4;
  const int sw = ml & 7;

#define KSTEP(APTR, ASTRIDE)                                                       \
  {                                                                                \
    __syncthreads();                                                               \
    _Pragma("unroll")                                                              \
    for (int ib = 0; ib < 4; ++ib)                                                 \
      async_load16(APTR + (size_t)ib * 8 * (ASTRIDE), &Asm[wave * 32 + ib * 8][0]);\
    _Pragma("unroll")                                                              \
    for (int ib = 0; ib < 4; ++ib)                                                 \
      async_load16(bg + (size_t)ib * 8 * GK, &Bsm[wave * 32 + ib * 8][0]);         \
    bg += 64;                                                                      \
    __syncthreads();                                                               \
    _Pragma("unroll")                                                              \
    for (int ks = 0; ks < 2; ++ks) {                                               \
      const int go = (((ks * 4 + quad) ^ sw) * 8);                                 \
      short8 a[4], b[4];                                                           \
      _Pragma("unroll")                                                            \
      for (int i = 0; i < 4; ++i) a[i] = *(const short8*)&Asm[wm + i * 16 + ml][go];\
      _Pragma("unroll")                                                            \
      for (int i = 0; i < 4; ++i) b[i] = *(const short8*)&Bsm[wn + i * 16 + ml][go];\
      _Pragma("unroll")                                                            \
      for (int i = 0; i < 4; ++i)                                                  \
        _Pragma("unroll")                                                          \
        for (int j = 0; j < 4; ++j)                                                \
          acc[i][j] = __builtin_amdgcn_mfma_f32_16x16x32_bf16(a[i], b[j], acc[i][j], 0, 0, 0); \
    }                                                                              \
  }

  for (int kt = 0; kt < GKA / 64; ++kt) {   // 96 k-tiles from mean buffer
    KSTEP(ag, GKA);
    ag += 64;
  }
  for (int kt = 0; kt < DIM / 64; ++kt) {   // 12 k-tiles from root operand
    KSTEP(fg, DIM);
    fg += 64;
  }
#undef KSTEP

  float bcol[4];
#pragma unroll
  for (int nt = 0; nt < 4; ++nt) bcol[nt] = bias[n0 + wn + nt * 16 + ml];
#pragma unroll
  for (int mt = 0; mt < 4; ++mt) {
#pragma unroll
    for (int rr = 0; rr < 4; ++rr) {
      int row = m0 + wm + mt * 16 + quad * 4 + rr;
      if (row < mvalid) {
        size_t orow = (size_t)(node_base + row) * DIM;
#pragma unroll
        for (int nt = 0; nt < 4; ++nt) {
          int col = n0 + wn + nt * 16 + ml;
          float v = acc[mt][nt][rr] + bcol[nt];
          if (mode == 0) outb[orow + col] = __float2bfloat16(fmaxf(v, 0.f));
          else           outf[orow + col] = v;
        }
      }
    }
  }
}

// ---------------------------------------------------------------- launch
extern "C" void kernel_launch(void* const* d_in, const int* in_sizes, int n_in,
                              void* d_out, int out_size, void* d_ws, size_t ws_size,
                              hipStream_t stream) {
  const float* x     = (const float*)d_in[0];
  const int*   eidx  = (const int*)d_in[1];     // [2][E]
  const int*   etype = (const int*)d_in[2];
  const float* W1    = (const float*)d_in[3];
  const float* root1 = (const float*)d_in[4];
  const float* b1    = (const float*)d_in[5];
  const float* W2    = (const float*)d_in[6];
  const float* root2 = (const float*)d_in[7];
  const float* b2    = (const float*)d_in[8];
  float* out = (float*)d_out;
  const int* esrc_in = eidx;
  const int* edst_in = eidx + NEDGE;

  char* p = (char*)d_ws;
  auto alloc = [&](size_t bytes) -> char* {
    char* r = p;
    p += (bytes + 255) & ~(size_t)255;
    return r;
  };
  __hip_bfloat16* xb  = (__hip_bfloat16*)alloc((size_t)N_NODES * DIM * 2);
  __hip_bfloat16* hb  = (__hip_bfloat16*)alloc((size_t)N_NODES * DIM * 2);
  __hip_bfloat16* w1t = (__hip_bfloat16*)alloc((size_t)DIM * GK * 2);
  __hip_bfloat16* w2t = (__hip_bfloat16*)alloc((size_t)DIM * GK * 2);
  int* segcnt   = (int*)alloc((size_t)NSEG * 4);
  int* soffs    = (int*)alloc((size_t)(NSEG + 1) * 4);
  int* cursor   = (int*)alloc((size_t)NSEG * 4);
  int* partials = (int*)alloc(256 * 4);
  int* es       = (int*)alloc((size_t)NEDGE * 4);
  size_t used = (size_t)(p - (char*)d_ws);
  size_t remain = (ws_size > used) ? (ws_size - used) : 0;
  long long caprows_ll = (long long)(remain / ((size_t)GKA * 2));
  int caprows = (int)((caprows_ll / 128) * 128);
  if (caprows > 20096) caprows = 20096;   // 157*128
  if (caprows < 128) caprows = 128;
  __hip_bfloat16* Abuf = (__hip_bfloat16*)p;

  // --- segment CSR build (edges sorted by (dst, rel)) ---
  const int NB = (NSEG + 1023) / 1024;    // 157
  hipMemsetAsync(segcnt, 0, (size_t)NSEG * 4, stream);
  seg_count_kernel<<<(NEDGE + 255) / 256, 256, 0, stream>>>(edst_in, etype, segcnt, NEDGE);
  block_scan_kernel<<<NB, 1024, 0, stream>>>(segcnt, soffs, partials, NSEG);
  partial_scan_kernel<<<1, 64, 0, stream>>>(partials, NB);
  add_offsets_kernel<<<NB, 1024, 0, stream>>>(soffs, partials, cursor, NSEG);
  seg_scatter_kernel<<<(NEDGE + 255) / 256, 256, 0, stream>>>(esrc_in, edst_in, etype, cursor, es, NEDGE);

  // --- convert x, build transposed bf16 weights ---
  cvt_bf16_kernel<<<((N_NODES * DIM / 4) + 255) / 256, 256, 0, stream>>>(
      (const float4*)x, (ushort4*)xb, N_NODES * DIM / 4);
  dim3 tb(32, 8);
  transpose_w_kernel<<<dim3(DIM / 32, (NREL * DIM) / 32), tb, 0, stream>>>(W1, w1t, NREL * DIM, 0);
  transpose_w_kernel<<<dim3(DIM / 32, DIM / 32), tb, 0, stream>>>(root1, w1t, DIM, NREL * DIM);
  transpose_w_kernel<<<dim3(DIM / 32, (NREL * DIM) / 32), tb, 0, stream>>>(W2, w2t, NREL * DIM, 0);
  transpose_w_kernel<<<dim3(DIM / 32, DIM / 32), tb, 0, stream>>>(root2, w2t, DIM, NREL * DIM);

  // --- layer 1: h = relu([mean_r(x) | x] @ W1cat + b1) -> bf16 ---
  for (int base = 0; base < N_NODES; base += caprows) {
    int rows = N_NODES - base; if (rows > caprows) rows = caprows;
    int agrid = (rows + 4 * NPW - 1) / (4 * NPW);
    aggregate_kernel<<<agrid, 256, 0, stream>>>(xb, soffs, es, Abuf, base, rows);
    dim3 grid(DIM / 128, (rows + 127) / 128);
    gemm_kernel<<<grid, 256, 0, stream>>>(Abuf, xb, w1t, b1, hb, nullptr, rows, base, 0);
  }
  // --- layer 2: out = [mean_r(h) | h] @ W2cat + b2 -> f32 ---
  for (int base = 0; base < N_NODES; base += caprows) {
    int rows = N_NODES - base; if (rows > caprows) rows = caprows;
    int agrid = (rows + 4 * NPW - 1) / (4 * NPW);
    aggregate_kernel<<<agrid, 256, 0, stream>>>(hb, soffs, es, Abuf, base, rows);
    dim3 grid(DIM / 128, (rows + 127) / 128);
    gemm_kernel<<<grid, 256, 0, stream>>>(Abuf, hb, w2t, b2, nullptr, out, rows, base, 1);
  }
}